// Round 6
// baseline (18.028 us; speedup 1.0000x reference)
//
#include <hip/hip_runtime.h>
#include <hip/hip_bf16.h>

// ZeroOneLoss: out = mean_i( input[i, targets[i]] > 0 ),  B=16384, V=32000.
//
// SINGLE regular graph node. R5 refinement: per-WAVE flag publish removes
// LDS + __syncthreads from the gather critical path.
//   blocks 0..63  : 4 waves x 64 rows each. Each wave: coalesced target
//                   load -> scattered input load -> ballot -> lane 0
//                   device-scope atomic-stores (0x5A5A0000 | popcount)
//                   into flags[b*4 + wave].
//   block 64      : first wave polls the 256 per-wave flags (4/lane) with
//                   device-scope atomic loads, sums the 16-bit partials
//                   (exact int sum -> deterministic), writes out[0], and
//                   resets flags to 0 for the next graph replay.
//
// Safety:
//  - One-way wait (gatherers never wait) -> deadlock-free regardless of
//    dispatch order / co-residency.
//  - Poison 0xAAAAAAAA can't spoof signature 0x5A5Axxxx -> first replay
//    after poisoning is correct; reducer's reset handles later replays.
//  - Plain overwrite of d_out -> no memset node, no atomics into out.

#define ZOL_SIG 0x5A5A0000u

__global__ __launch_bounds__(256) void zol_fused(
        const float* __restrict__ input,
        const int* __restrict__ targets,
        float* __restrict__ out,
        unsigned int* __restrict__ flags,
        int B, long long V, int nGather) {
    const int b = blockIdx.x;
    const int tid = threadIdx.x;

    if (b < nGather) {
        // ---- gather block: no LDS, no __syncthreads ----
        int i = b * 256 + tid;
        bool pred = false;
        if (i < B) {
            int t = targets[i];
            pred = input[(long long)i * V + (long long)t] > 0.0f;
        }
        unsigned long long m = __ballot(pred);
        if ((tid & 63) == 0) {
            __hip_atomic_store(&flags[b * 4 + (tid >> 6)],
                               ZOL_SIG | (unsigned)__popcll(m),
                               __ATOMIC_RELEASE, __HIP_MEMORY_SCOPE_AGENT);
        }
    } else {
        // ---- reducer block (first wave only) ----
        if (tid < 64) {
            const int nFlags = nGather * 4;
            int v = 0;
            for (int j = tid; j < nFlags; j += 64) {
                unsigned f;
                do {
                    f = __hip_atomic_load(&flags[j], __ATOMIC_ACQUIRE,
                                          __HIP_MEMORY_SCOPE_AGENT);
                } while ((f & 0xFFFF0000u) != ZOL_SIG);
                v += (int)(f & 0xFFFFu);
                __hip_atomic_store(&flags[j], 0u,
                                   __ATOMIC_RELAXED, __HIP_MEMORY_SCOPE_AGENT);
            }
            #pragma unroll
            for (int off = 32; off > 0; off >>= 1)
                v += __shfl_down(v, off, 64);
            if (tid == 0)
                out[0] = (float)v / (float)B;
        }
    }
}

extern "C" void kernel_launch(void* const* d_in, const int* in_sizes, int n_in,
                              void* d_out, int out_size, void* d_ws, size_t ws_size,
                              hipStream_t stream) {
    const float* input = (const float*)d_in[0];
    const int* targets = (const int*)d_in[1];
    float* out = (float*)d_out;

    const int B = in_sizes[1];                                   // 16384
    const long long V = (long long)in_sizes[0] / (long long)B;   // 32000
    unsigned int* flags = (unsigned int*)d_ws;

    const int nGather = (B + 255) / 256;                         // 64
    zol_fused<<<nGather + 1, 256, 0, stream>>>(input, targets, out, flags,
                                               B, V, nGather);
}

// Round 7
// 9.749 us; speedup vs baseline: 1.8491x; 1.8491x over previous
//
#include <hip/hip_runtime.h>
#include <hip/hip_bf16.h>

// ZeroOneLoss: out = mean_i( input[i, targets[i]] > 0 ),  B=16384, V=32000.
//
// SINGLE regular graph node (R5 design — best measured: 12.05 us).
// R6's per-wave flags regressed to 18 us (4x flags -> reducer's sequential
// per-lane acquire-polls serialize ~4 cross-XCD round trips; 4x contended
// device-scope stores). Reverted to block-level flags.
//
//   blocks 0..63  : gather 256 rows each (spread across CUs -> one HBM/L3
//                   latency shot), ballot -> LDS -> tid0 publishes
//                   (0x5A5A0000 | block_count) into flags[b] with a
//                   device-scope atomic store (cross-XCD coherent).
//   block 64      : first wave polls the 64 flags (1/lane) with
//                   device-scope atomic loads, sums the 16-bit partials
//                   (exact int sum -> deterministic), writes out[0], and
//                   resets flags to 0 for the next graph replay.
//
// Safety:
//  - One-way wait (gatherers never wait) -> deadlock-free regardless of
//    dispatch order / co-residency.
//  - Poison 0xAAAAAAAA can't spoof signature 0x5A5Axxxx -> first replay
//    after poisoning is correct; reducer's reset handles later replays.
//  - Plain overwrite of d_out -> no memset node, no atomics into out.

#define ZOL_SIG 0x5A5A0000u

__global__ __launch_bounds__(256) void zol_fused(
        const float* __restrict__ input,
        const int* __restrict__ targets,
        float* __restrict__ out,
        unsigned int* __restrict__ flags,
        int B, long long V, int nGather) {
    const int b = blockIdx.x;
    const int tid = threadIdx.x;

    if (b < nGather) {
        // ---- gather block ----
        int i = b * 256 + tid;
        bool pred = false;
        if (i < B) {
            int t = targets[i];
            pred = input[(long long)i * V + (long long)t] > 0.0f;
        }
        unsigned long long m = __ballot(pred);
        __shared__ int wsum[4];
        const int lane = tid & 63, wid = tid >> 6;
        if (lane == 0) wsum[wid] = (int)__popcll(m);
        __syncthreads();
        if (tid == 0) {
            unsigned tot = (unsigned)(wsum[0] + wsum[1] + wsum[2] + wsum[3]);
            __hip_atomic_store(&flags[b], ZOL_SIG | tot,
                               __ATOMIC_RELEASE, __HIP_MEMORY_SCOPE_AGENT);
        }
    } else {
        // ---- reducer block (first wave only) ----
        if (tid < 64) {
            int v = 0;
            for (int j = tid; j < nGather; j += 64) {
                unsigned f;
                do {
                    f = __hip_atomic_load(&flags[j], __ATOMIC_ACQUIRE,
                                          __HIP_MEMORY_SCOPE_AGENT);
                } while ((f & 0xFFFF0000u) != ZOL_SIG);
                v += (int)(f & 0xFFFFu);
                __hip_atomic_store(&flags[j], 0u,
                                   __ATOMIC_RELAXED, __HIP_MEMORY_SCOPE_AGENT);
            }
            #pragma unroll
            for (int off = 32; off > 0; off >>= 1)
                v += __shfl_down(v, off, 64);
            if (tid == 0)
                out[0] = (float)v / (float)B;
        }
    }
}

extern "C" void kernel_launch(void* const* d_in, const int* in_sizes, int n_in,
                              void* d_out, int out_size, void* d_ws, size_t ws_size,
                              hipStream_t stream) {
    const float* input = (const float*)d_in[0];
    const int* targets = (const int*)d_in[1];
    float* out = (float*)d_out;

    const int B = in_sizes[1];                                   // 16384
    const long long V = (long long)in_sizes[0] / (long long)B;   // 32000
    unsigned int* flags = (unsigned int*)d_ws;

    const int nGather = (B + 255) / 256;                         // 64
    zol_fused<<<nGather + 1, 256, 0, stream>>>(input, targets, out, flags,
                                               B, V, nGather);
}